// Round 4
// baseline (648.971 us; speedup 1.0000x reference)
//
#include <hip/hip_runtime.h>
#include <hip/hip_bf16.h>

typedef unsigned int u32;
typedef unsigned short u16;

typedef _Float16 half2_t __attribute__((ext_vector_type(2)));
union H2U { u32 u; half2_t h; };

typedef _Float16 f16x8 __attribute__((ext_vector_type(8)));
typedef float f32x4 __attribute__((ext_vector_type(4)));
union F16V { uint4 u; f16x8 h; };

#if defined(__has_builtin)
#if __has_builtin(__builtin_amdgcn_fdot2)
#define HAS_FDOT2 1
#endif
#if __has_builtin(__builtin_amdgcn_update_dpp)
#define HAS_DPP 1
#endif
#endif

__device__ __forceinline__ float bf2f(u32 u) {
  union { u32 i; float f; } v; v.i = u << 16; return v.f;
}
__device__ __forceinline__ float sigf(float x) {
  return 1.0f / (1.0f + __expf(-x));
}
__device__ __forceinline__ float tanhfast(float x) {
  return 2.0f / (1.0f + __expf(-2.0f * x)) - 1.0f;
}
__device__ __forceinline__ u16 f2bf(float f) {
  u32 u = __float_as_uint(f);
  u += 0x7fffu + ((u >> 16) & 1u);
  return (u16)(u >> 16);
}
__device__ __forceinline__ u16 f2h(float f) {
  union { _Float16 h; u16 u; } v; v.h = (_Float16)f; return v.u;
}
__device__ __forceinline__ u32 fpair2h2(float a, float b) {
  H2U r; r.h.x = (_Float16)a; r.h.y = (_Float16)b; return r.u;
}
__device__ __forceinline__ u32 bfpair2h2(u32 two_bf) {
  H2U r;
  r.h.x = (_Float16)bf2f(two_bf & 0xffffu);
  r.h.y = (_Float16)bf2f(two_bf >> 16);
  return r.u;
}
__device__ __forceinline__ float dot2acc(u32 wu, u32 hu, float acc) {
  H2U w, h; w.u = wu; h.u = hu;
#ifdef HAS_FDOT2
  return __builtin_amdgcn_fdot2(w.h, h.h, acc, false);
#else
  acc = fmaf((float)w.h.x, (float)h.h.x, acc);
  return fmaf((float)w.h.y, (float)h.h.y, acc);
#endif
}
// DPP cross-lane move (VALU pipe, not DS). Controls used:
//   0xB1 quad_perm[1,0,3,2] (xor 1), 0x4E quad_perm[2,3,0,1] (xor 2),
//   0x00/0x55/0xAA/0xFF quad broadcast lane k,
//   0x104: dst[i]=src[i+4] (empirically verified: rounds 1-3 passed with this
//          implementing shfl_down 4), 0x114: dst[i]=src[i-4] (the converse).
template <int CTRL>
__device__ __forceinline__ float dppf(float x) {
#ifdef HAS_DPP
  int y = __builtin_amdgcn_update_dpp(0, __float_as_int(x), CTRL, 0xF, 0xF, true);
  return __int_as_float(y);
#else
  const int lane = threadIdx.x & 63;
  if (CTRL == 0xB1)  return __shfl_xor(x, 1, 64);
  if (CTRL == 0x4E)  return __shfl_xor(x, 2, 64);
  if (CTRL == 0x104) return __shfl_down(x, 4, 64);
  if (CTRL == 0x114) return __shfl_up(x, 4, 64);
  return __shfl(x, (lane & ~3) | (CTRL & 3), 64);  // quad broadcast
#endif
}

// ---- runtime dtype detection (bf16 vs fp32 inputs) ----
__global__ void k_detect(const u32* __restrict__ w, int* __restrict__ flag) {
  __shared__ int cnt;
  if (threadIdx.x == 0) cnt = 0;
  __syncthreads();
  int c = 0;
  for (int i = threadIdx.x; i < 8192; i += 256) {
    const u32 lo = w[i] & 0xffffu;
    const u32 e = (lo >> 7) & 0xffu;
    c += (e >= 100u && e <= 140u) ? 1 : 0;
  }
  atomicAdd(&cnt, c);
  __syncthreads();
  if (threadIdx.x == 0) *flag = (cnt > 4915) ? 1 : 0;
}

struct Job { const void* s; float* d; int n; int f16; };
struct Jobs { Job j[30]; };

__global__ void k_cvt_all(Jobs J, const int* __restrict__ flag) {
  const Job jb = J.j[blockIdx.y];
  const int isbf = *flag;
  for (int i = blockIdx.x * 256 + threadIdx.x; i < jb.n; i += 32 * 256) {
    const float v = isbf ? bf2f(((const u16*)jb.s)[i]) : ((const float*)jb.s)[i];
    if (jb.f16) ((u16*)jb.d)[i] = f2h(v);
    else        jb.d[i] = v;
  }
}

// 4 bias-broadcast inits in one dispatch
struct IJobs { const float* b[4]; float* d[4]; int n[4]; int mask[4]; };
__global__ void k_init4(IJobs I) {
  const int j = blockIdx.y;
  const float* bb = I.b[j];
  float* dd = I.d[j];
  const int n = I.n[j], mask = I.mask[j];
  for (int i = blockIdx.x * 256 + threadIdx.x; i < n; i += gridDim.x * 256)
    dd[i] = bb[i & mask];
}

// Pack staged fp32 recurrent weights into the 8-chunk per-thread f16-pair
// layout consumed by k_rec v2: thread tid = (rp = tid>>3, c8 = tid&7) owns
// rows {2rp, 2rp+1} x k-chunk c8 (16 h values):
//   dst[tid*64 + row01*32 + j*8 + kk] =
//     pack(W[2rp+row01+128j][16c8+2kk], W[..][16c8+2kk+1]).
// Optional second source s2 -> element-wise sum (decoder Wih+Whh).
struct PJobs { const float* s[7]; const float* s2[7]; u32* d[7]; };
__global__ void k_pack(PJobs P) {
  const float* src = P.s[blockIdx.y];
  const float* src2 = P.s2[blockIdx.y];
  u32* dst = P.d[blockIdx.y];
  const int i = blockIdx.x * 256 + threadIdx.x;   // 0..32767
  const int tid = i >> 6, rem = i & 63;
  const int row01 = rem >> 5, j = (rem >> 3) & 3, kk = rem & 7;
  const int rp = tid >> 3, c8 = tid & 7;
  const int row = 2 * rp + row01 + 128 * j;
  const int col = 16 * c8 + 2 * kk;
  float v0 = src[row * 128 + col];
  float v1 = src[row * 128 + col + 1];
  if (src2) { v0 += src2[row * 128 + col]; v1 += src2[row * 128 + col + 1]; }
  H2U v;
  v.h.x = (_Float16)v0;
  v.h.y = (_Float16)v1;
  dst[i] = v.u;
}

// MFMA f16 GEMM: C[M,N] (+)= A[M,K] @ W[N,K]^T (+bias).
// A: f16 (u16) row-major. W: bf16-u16 or fp32 (wfollow: runtime detect; else
// fp32 staged), converted to f16 in-flight (exact for bf16 at these ranges).
// 64x64 tile, 4 waves x (2x2) 16x16x32 frags, LDS rows padded to 40 u16
// (80 B = 20 banks -> worst 2-way = free). Verified C/D map: col=lane&15,
// row=(lane>>4)*4+reg.
__launch_bounds__(256)
__global__ void k_mf(const u16* __restrict__ A, int lda,
                     const void* __restrict__ Wv, int ldw,
                     const float* __restrict__ bias,
                     float* __restrict__ C, int ldc,
                     int K, int atom, int wfollow,
                     const int* __restrict__ dflag)
{
  __shared__ __align__(16) u16 As[64][40];
  __shared__ __align__(16) u16 Bs[64][40];
  const int isbf = wfollow ? *dflag : 0;
  const int tid = threadIdx.x;
  const int m0 = blockIdx.x * 64, n0 = blockIdx.y * 64;
  const int kc = K / gridDim.z;
  const int k0 = blockIdx.z * kc;
  const int row = tid >> 2, part = tid & 3;       // staging: 8 cols of one row
  const int l = tid & 63, w = tid >> 6;
  const int wr = w >> 1, wc = w & 1;              // wave tile origin /32
  const int fr = l & 15, fk = l >> 4;             // fragment row/col, k-group
  f32x4 acc[2][2] = {};
  const u16*   Ap   = A + (size_t)(m0 + row) * lda + k0 + part * 8;
  const u16*   Wp16 = (const u16*)Wv   + (size_t)(n0 + row) * ldw + k0 + part * 8;
  const float* Wp32 = (const float*)Wv + (size_t)(n0 + row) * ldw + k0 + part * 8;

  for (int kk = 0; kk < kc; kk += 32) {
    const uint4 av = *(const uint4*)(Ap + kk);
    uint4 wv;
    if (isbf) {
      const uint4 wu = *(const uint4*)(Wp16 + kk);
      wv.x = bfpair2h2(wu.x); wv.y = bfpair2h2(wu.y);
      wv.z = bfpair2h2(wu.z); wv.w = bfpair2h2(wu.w);
    } else {
      const float4 w0 = *(const float4*)(Wp32 + kk);
      const float4 w1 = *(const float4*)(Wp32 + kk + 4);
      wv.x = fpair2h2(w0.x, w0.y); wv.y = fpair2h2(w0.z, w0.w);
      wv.z = fpair2h2(w1.x, w1.y); wv.w = fpair2h2(w1.z, w1.w);
    }
    __syncthreads();
    *(uint4*)&As[row][part * 8] = av;
    *(uint4*)&Bs[row][part * 8] = wv;
    __syncthreads();
    F16V a0, a1, b0, b1;
    a0.u = *(const uint4*)&As[wr * 32 + fr][fk * 8];
    a1.u = *(const uint4*)&As[wr * 32 + 16 + fr][fk * 8];
    b0.u = *(const uint4*)&Bs[wc * 32 + fr][fk * 8];
    b1.u = *(const uint4*)&Bs[wc * 32 + 16 + fr][fk * 8];
    acc[0][0] = __builtin_amdgcn_mfma_f32_16x16x32_f16(a0.h, b0.h, acc[0][0], 0, 0, 0);
    acc[0][1] = __builtin_amdgcn_mfma_f32_16x16x32_f16(a0.h, b1.h, acc[0][1], 0, 0, 0);
    acc[1][0] = __builtin_amdgcn_mfma_f32_16x16x32_f16(a1.h, b0.h, acc[1][0], 0, 0, 0);
    acc[1][1] = __builtin_amdgcn_mfma_f32_16x16x32_f16(a1.h, b1.h, acc[1][1], 0, 0, 0);
  }

  #pragma unroll
  for (int i = 0; i < 2; ++i) {
    #pragma unroll
    for (int j = 0; j < 2; ++j) {
      const int n = n0 + wc * 32 + j * 16 + fr;
      const float bv = (bias && !atom) ? bias[n] : 0.0f;
      #pragma unroll
      for (int q = 0; q < 4; ++q) {
        const int m = m0 + wr * 32 + i * 16 + fk * 4 + q;
        if (atom) atomicAdd(&C[(size_t)m * ldc + n], acc[i][j][q]);
        else      C[(size_t)m * ldc + n] = acc[i][j][q] + bv;
      }
    }
  }
}

// C[M,N] (+)= A[M,K] @ W[N,K]^T (+bias). fp32 scalar path — retained for the
// small proj + MLP-tail layers (actA tanh on A, fp32 accumulate).
__launch_bounds__(256)
__global__ void k_gemm(const float* __restrict__ A, int lda,
                       const void* __restrict__ Wv, int ldw,
                       const float* __restrict__ bias,
                       float* __restrict__ C, int ldc,
                       int K, int actA, int atom, int wfollow,
                       const int* __restrict__ dflag)
{
  __shared__ float As[32][65];
  __shared__ float Ws[32][65];
  const int isbf = wfollow ? *dflag : 0;
  const int tid = threadIdx.x;
  const int tx = tid & 15, ty = tid >> 4;
  const int m0 = blockIdx.x * 64, n0 = blockIdx.y * 64;
  const int kc = K / gridDim.z;
  const int k0 = blockIdx.z * kc;
  const int lr = tid >> 2;
  const int lk = (tid & 3) << 3;
  float acc[4][4] = {{0.f}};
  const float* Ap   = A + (size_t)(m0 + lr) * lda + k0 + lk;
  const u16*   Wp16 = (const u16*)Wv   + (size_t)(n0 + lr) * ldw + k0 + lk;
  const float* Wp32 = (const float*)Wv + (size_t)(n0 + lr) * ldw + k0 + lk;
  for (int kk = 0; kk < kc; kk += 32) {
    float4 av0 = *(const float4*)(Ap + kk);
    float4 av1 = *(const float4*)(Ap + kk + 4);
    float wv[8];
    if (isbf) {
      const uint4 wu = *(const uint4*)(Wp16 + kk);
      wv[0]=bf2f(wu.x & 0xffffu); wv[1]=bf2f(wu.x >> 16);
      wv[2]=bf2f(wu.y & 0xffffu); wv[3]=bf2f(wu.y >> 16);
      wv[4]=bf2f(wu.z & 0xffffu); wv[5]=bf2f(wu.z >> 16);
      wv[6]=bf2f(wu.w & 0xffffu); wv[7]=bf2f(wu.w >> 16);
    } else {
      const float4 w0 = *(const float4*)(Wp32 + kk);
      const float4 w1 = *(const float4*)(Wp32 + kk + 4);
      wv[0]=w0.x; wv[1]=w0.y; wv[2]=w0.z; wv[3]=w0.w;
      wv[4]=w1.x; wv[5]=w1.y; wv[6]=w1.z; wv[7]=w1.w;
    }
    if (actA) {
      av0.x = tanhfast(av0.x); av0.y = tanhfast(av0.y);
      av0.z = tanhfast(av0.z); av0.w = tanhfast(av0.w);
      av1.x = tanhfast(av1.x); av1.y = tanhfast(av1.y);
      av1.z = tanhfast(av1.z); av1.w = tanhfast(av1.w);
    }
    __syncthreads();
    As[lk+0][lr] = av0.x; As[lk+1][lr] = av0.y;
    As[lk+2][lr] = av0.z; As[lk+3][lr] = av0.w;
    As[lk+4][lr] = av1.x; As[lk+5][lr] = av1.y;
    As[lk+6][lr] = av1.z; As[lk+7][lr] = av1.w;
    #pragma unroll
    for (int q = 0; q < 8; ++q) Ws[lk+q][lr] = wv[q];
    __syncthreads();
    #pragma unroll
    for (int k = 0; k < 32; ++k) {
      float a[4], w[4];
      #pragma unroll
      for (int i = 0; i < 4; ++i) a[i] = As[k][ty + 16*i];
      #pragma unroll
      for (int j = 0; j < 4; ++j) w[j] = Ws[k][tx + 16*j];
      #pragma unroll
      for (int i = 0; i < 4; ++i)
        #pragma unroll
        for (int j = 0; j < 4; ++j)
          acc[i][j] = fmaf(a[i], w[j], acc[i][j]);
    }
  }
  #pragma unroll
  for (int i = 0; i < 4; ++i) {
    const int m = m0 + ty + 16*i;
    #pragma unroll
    for (int j = 0; j < 4; ++j) {
      const int n = n0 + tx + 16*j;
      if (atom) atomicAdd(&C[(size_t)m*ldc + n], acc[i][j]);
      else {
        const float bv = bias ? bias[n] : 0.0f;
        C[(size_t)m*ldc + n] = acc[i][j] + bv;
      }
    }
  }
}

// Recurrence v3 — 8-chunk thread map, DS 6 -> 4 insts/wave/step.
// Thread (rp = tid>>3, c8 = tid&7): owns rows {2rp, 2rp+1}, k-chunk c8
// (16 h values = 8 packed u32). Per step:
//   2x ds_read_b128 hbuf (was 4; padded layout, conflict-free),
//   1x ds_read_b64 zc (both rows' z for this lane's gate; 2-way max = free),
//   1x ds_write_b32 (c8==0 packs both rows' f16 h locally — no shfl_down).
// Gate-spread: quad transpose-reduce (proven r1-r3) + one cross-quad i^4
// exchange (0x104/0x114 DPP pair + select). Barrier: __syncthreads (round-3's
// lgkm-only barrier measured SLOWER — reverted).
__launch_bounds__(512)
__attribute__((amdgpu_waves_per_eu(2, 2)))
__global__ void k_rec(const float* __restrict__ Zf, const float* __restrict__ Zb,
                      const u32* __restrict__ Wf, const u32* __restrict__ Wb,
                      float* __restrict__ HS, int hstride, int offF, int offB,
                      const float* __restrict__ h0, const float* __restrict__ c0,
                      int zmode, int zld, float* __restrict__ Cout, int hf16)
{
  const int b = blockIdx.x & 63;
  const int dir = blockIdx.x >> 6;
  const float* Z = dir ? Zb : Zf;
  const u32* Wg = dir ? Wb : Wf;
  const int off = dir ? offB : offF;
  const int tid = threadIdx.x;
  const int rp = tid >> 3, c8 = tid & 7;
  const int g = c8 & 3, hi = c8 >> 2;

  __shared__ __align__(16) float zall[64*512];   // 128 KB staged Z (read-only in loop)
  __shared__ __align__(16) u32 hbuf[2][68];      // packed f16 h; +4 pad per half

  // --- bulk stage Z into LDS (coalesced float4), gate*8-element XOR swizzle ---
  if (!zmode) {
    #pragma unroll
    for (int q = 0; q < 16; ++q) {
      const int fid = tid + 512*q;
      const int s = fid >> 7, c4 = (fid & 127) << 2;
      const int cs = c4 ^ ((c4 >> 7) << 3);
      *(float4*)&zall[s*512 + cs] = *(const float4*)&Z[((size_t)s*64 + b)*zld + c4];
    }
  }

  u32 wp[64];
  {
    const uint4* wr = (const uint4*)(Wg + (size_t)tid * 64);
    #pragma unroll
    for (int q = 0; q < 16; ++q) {
      const uint4 u = wr[q];
      wp[q*4+0]=u.x; wp[q*4+1]=u.y; wp[q*4+2]=u.z; wp[q*4+3]=u.w;
    }
  }
  #pragma unroll
  for (int q = 0; q < 64; ++q)
    asm volatile("" : "+v"(wp[q]));

  float creg0 = c0 ? c0[b*128 + 2*rp]     : 0.0f;
  float creg1 = c0 ? c0[b*128 + 2*rp + 1] : 0.0f;
  if (tid < 64) {
    H2U v;
    if (h0) {
      v.h.x = (_Float16)h0[b*128 + 2*tid];
      v.h.y = (_Float16)h0[b*128 + 2*tid + 1];
    } else {
      v.h.x = (_Float16)0.f; v.h.y = (_Float16)0.f;
    }
    hbuf[0][tid + ((tid >> 5) << 2)] = v.u;
  }

  // per-thread zc slot: gate g, rows 2rp/2rp+1 (matches staging swizzle)
  const int zc_e = (2*rp + 128*g) ^ (g << 3);
  float zdec0 = 0.f, zdec1 = 0.f;
  if (zmode) { zdec0 = Z[2*rp + 128*g]; zdec1 = Z[2*rp + 1 + 128*g]; }
  const float* zp = zall + (dir ? 63*512 : 0) + zc_e;
  const int zstep = dir ? -512 : 512;
  size_t hidx = ((size_t)(dir ? 63 : 0)*64 + b)*hstride + off + 2*rp;
  const ptrdiff_t hstep = (ptrdiff_t)(dir ? -64 : 64) * hstride;
  const bool beta = (c8 & 1) != 0;
  const bool gmm  = (c8 & 2) != 0;
  const int hbase = c8*8 + (hi << 2);            // padded chunk base (u32)
  const int hwidx = rp + ((rp >> 5) << 2);       // padded write slot
  __syncthreads();

  for (int t = 0; t < 64; ++t) {
    float zc0, zc1;
    if (zmode) { zc0 = zdec0; zc1 = zdec1; }
    else { const float2 z2 = *(const float2*)zp; zc0 = z2.x; zc1 = z2.y; }
    u32 hh8[8];
    {
      const u32* hp = &hbuf[t & 1][hbase];
      *(uint4*)&hh8[0] = *(const uint4*)&hp[0];
      *(uint4*)&hh8[4] = *(const uint4*)&hp[4];
    }
    float a0[4] = {0.f,0.f,0.f,0.f};
    float a1[4] = {0.f,0.f,0.f,0.f};
    #pragma unroll
    for (int j = 0; j < 4; ++j)
      #pragma unroll
      for (int i = 0; i < 8; ++i) {
        a0[j] = dot2acc(wp[j*8 + i],      hh8[i], a0[j]);
        a1[j] = dot2acc(wp[32 + j*8 + i], hh8[i], a1[j]);
      }
    // quad transpose-reduce (lane ends with gate g over its quad's 4 chunks),
    // then cross-quad i^4 exchange for the full 128-k dot.
    float gf0, gf1;
    {
      const float u0 = beta ? a0[1] : a0[0];
      const float v0 = beta ? a0[0] : a0[1];
      const float u1 = beta ? a0[3] : a0[2];
      const float v1 = beta ? a0[2] : a0[3];
      const float x01 = u0 + dppf<0xB1>(v0);
      const float x23 = u1 + dppf<0xB1>(v1);
      const float q = (gmm ? x23 : x01) + dppf<0x4E>(gmm ? x01 : x23);
      const float ep = dppf<0x104>(q);   // src[i+4] (for hi=0)
      const float em = dppf<0x114>(q);   // src[i-4] (for hi=1)
      gf0 = q + (hi ? em : ep) + zc0;
    }
    {
      const float u0 = beta ? a1[1] : a1[0];
      const float v0 = beta ? a1[0] : a1[1];
      const float u1 = beta ? a1[3] : a1[2];
      const float v1 = beta ? a1[2] : a1[3];
      const float x01 = u0 + dppf<0xB1>(v0);
      const float x23 = u1 + dppf<0xB1>(v1);
      const float q = (gmm ? x23 : x01) + dppf<0x4E>(gmm ? x01 : x23);
      const float ep = dppf<0x104>(q);
      const float em = dppf<0x114>(q);
      gf1 = q + (hi ? em : ep) + zc1;
    }
    const float sg0 = sigf(gf0), tg0 = tanhfast(gf0);
    const float sg1 = sigf(gf1), tg1 = tanhfast(gf1);
    const float si0 = dppf<0x00>(sg0), sf0 = dppf<0x55>(sg0);
    const float tgg0 = dppf<0xAA>(tg0), so0 = dppf<0xFF>(sg0);
    const float si1 = dppf<0x00>(sg1), sf1 = dppf<0x55>(sg1);
    const float tgg1 = dppf<0xAA>(tg1), so1 = dppf<0xFF>(sg1);
    const float cc0 = sf0 * creg0 + si0 * tgg0;
    const float cc1 = sf1 * creg1 + si1 * tgg1;
    const float hh0 = so0 * tanhfast(cc0);
    const float hh1 = so1 * tanhfast(cc1);
    creg0 = cc0; creg1 = cc1;
    if (c8 == 0) {
      H2U v; v.h.x = (_Float16)hh0; v.h.y = (_Float16)hh1;
      if (hf16) ((u32*)HS)[hidx >> 1] = v.u;
      else { float2 o; o.x = hh0; o.y = hh1; *(float2*)&HS[hidx] = o; }
      hbuf[(t+1) & 1][hwidx] = v.u;
    }
    zp += zstep;
    hidx += hstep;
    __syncthreads();
  }

  if (Cout != nullptr && c8 == 0) {
    float2 o; o.x = creg0; o.y = creg1;
    *(float2*)&Cout[b*128 + 2*rp] = o;
  }
}

// Attention, fully parallel over (b, t-slice). flat is written as f16 (u16)
// — it feeds the MFMA W1 GEMM directly.
#define TS 132
__launch_bounds__(256, 1)
__global__ void k_att(const float* __restrict__ enco, const float* __restrict__ encp,
                      const float* __restrict__ Hdec, const float* __restrict__ Hproj,
                      const float* __restrict__ attw, u16* __restrict__ flat)
{
  const int b = blockIdx.x;
  const int t0 = blockIdx.y * 16;
  const int tid = threadIdx.x;
  __shared__ __align__(16) float ep[64*TS];
  __shared__ __align__(16) float en[64*TS];
  __shared__ __align__(16) float hp[16*TS];
  __shared__ float S[64*17];
  __shared__ float aw[64*17];
  __shared__ __align__(16) float awt[128];

  for (int i = tid; i < 8192; i += 256) {
    const int s = i >> 7, k = i & 127;
    const size_t g = ((size_t)s*64 + b)*128 + k;
    ep[s*TS + k] = encp[g];
    en[s*TS + k] = enco[g];
  }
  for (int i = tid; i < 2048; i += 256) {
    const int t = i >> 7, k = i & 127;
    const size_t g = ((size_t)(t0 + t)*64 + b)*128 + k;
    hp[t*TS + k] = Hproj[g];
    flat[(size_t)b*16384 + (t0 + t)*256 + k] = f2h(Hdec[g]);
  }
  if (tid < 128) awt[tid] = attw[tid];
  __syncthreads();

  {
    const int t = tid & 15, sg = tid >> 4;
    #pragma unroll
    for (int i = 0; i < 4; ++i) {
      const int s = sg*4 + i;
      float acc = 0.f;
      #pragma unroll 8
      for (int k = 0; k < 128; k += 4) {
        const float4 h4 = *(const float4*)&hp[t*TS + k];
        const float4 e4 = *(const float4*)&ep[s*TS + k];
        const float4 w4 = *(const float4*)&awt[k];
        acc = fmaf(w4.x, tanhfast(h4.x + e4.x), acc);
        acc = fmaf(w4.y, tanhfast(h4.y + e4.y), acc);
        acc = fmaf(w4.z, tanhfast(h4.z + e4.z), acc);
        acc = fmaf(w4.w, tanhfast(h4.w + e4.w), acc);
      }
      S[s*17 + t] = acc;
    }
  }
  __syncthreads();
  if (tid < 16) {
    const int t = tid;
    float m = -1e30f;
    for (int s = 0; s < 64; ++s) m = fmaxf(m, S[s*17 + t]);
    float sum = 0.f;
    for (int s = 0; s < 64; ++s) {
      const float e = __expf(S[s*17 + t] - m);
      aw[s*17 + t] = e;
      sum += e;
    }
    const float inv = 1.0f / sum;
    for (int s = 0; s < 64; ++s) aw[s*17 + t] *= inv;
  }
  __syncthreads();
  {
    const int t = tid >> 4, kg = tid & 15;
    float c0a[8] = {0,0,0,0,0,0,0,0};
    for (int s = 0; s < 64; ++s) {
      const float a = aw[s*17 + t];
      const float4 e0 = *(const float4*)&en[s*TS + kg*8];
      const float4 e1 = *(const float4*)&en[s*TS + kg*8 + 4];
      c0a[0] = fmaf(a, e0.x, c0a[0]);
      c0a[1] = fmaf(a, e0.y, c0a[1]);
      c0a[2] = fmaf(a, e0.z, c0a[2]);
      c0a[3] = fmaf(a, e0.w, c0a[3]);
      c0a[4] = fmaf(a, e1.x, c0a[4]);
      c0a[5] = fmaf(a, e1.y, c0a[5]);
      c0a[6] = fmaf(a, e1.z, c0a[6]);
      c0a[7] = fmaf(a, e1.w, c0a[7]);
    }
    union { u16 s[8]; uint4 u; } o;
    #pragma unroll
    for (int q = 0; q < 8; ++q) o.s[q] = f2h(c0a[q]);
    u16* dst = &flat[(size_t)b*16384 + (t0 + t)*256 + 128 + kg*8];
    *(uint4*)dst = o.u;
  }
}

__global__ void k_head(const float* __restrict__ a4, const float* __restrict__ outW,
                       const float* __restrict__ outb, void* __restrict__ out,
                       const int* __restrict__ dflag)
{
  const int b = threadIdx.x;
  float acc = outb[0];
  #pragma unroll 8
  for (int k = 0; k < 128; ++k)
    acc = fmaf(outW[k], tanhfast(a4[b*128 + k]), acc);
  if (*dflag) ((u16*)out)[b] = f2bf(acc);
  else        ((float*)out)[b] = acc;
}

extern "C" void kernel_launch(void* const* d_in, const int* in_sizes, int n_in,
                              void* d_out, int out_size, void* d_ws, size_t ws_size,
                              hipStream_t stream)
{
  (void)in_sizes; (void)n_in; (void)out_size; (void)ws_size;

  float* p = (float*)d_ws;
  int*   flagp = (int*)p;    p += 64;
  float* x0    = p; p += 64*64*64;          // f16 (u16)
  float* cl1Wih = p; p += 512*64;
  float* cl1Whh = p; p += 512*128;
  float* cl1b   = p; p += 512;
  float* c2Wih  = p; p += 1024*128;
  float* c2bias = p; p += 1024;
  float* c2fWhh = p; p += 512*128;
  float* c2bWhh = p; p += 512*128;
  float* c3Wih  = p; p += 1024*256;
  float* c3bias = p; p += 1024;
  float* c3fWhh = p; p += 512*128;
  float* c3bWhh = p; p += 512*128;
  float* ceWih  = p; p += 512*256;
  float* ceWhh  = p; p += 512*128;
  float* ceb    = p; p += 512;
  float* cdWih  = p; p += 512*128;
  float* cdWhh  = p; p += 512*128;
  float* cdb    = p; p += 512;
  float* cattW  = p; p += 128*128;
  float* cattw  = p; p += 128;
  float* cW1b   = p; p += 1024;
  float* cW2b   = p; p += 512;
  float* cW3b   = p; p += 256;
  float* cW4b   = p; p += 128;
  float* coW    = p; p += 128;
  float* cob    = p; p += 16;
  u32* wpL1 = (u32*)p; p += 32768;
  u32* wp2f = (u32*)p; p += 32768;
  u32* wp2b = (u32*)p; p += 32768;
  u32* wp3f = (u32*)p; p += 32768;
  u32* wp3b = (u32*)p; p += 32768;
  u32* wpE  = (u32*)p; p += 32768;
  u32* wpD  = (u32*)p; p += 32768;
  float* Zf   = p; p += 4096*512;
  float* Z2   = p; p += 4096*1024;
  float* h1   = p; p += 4096*128;           // f16 (u16)
  float* x2   = p; p += 4096*256;           // f16 (u16)
  float* x3   = p; p += 4096*256;           // f16 (u16)
  float* enco = p; p += 4096*128;   // enco and Hdec contiguous (merged proj A)
  float* Hdec = p; p += 4096*128;
  float* encp = p; p += 4096*128;   // encp and Hprj contiguous (merged proj C)
  float* Hprj = p; p += 4096*128;
  float* ec   = p; p += 64*128;
  float* flat = p; p += 64*16384;           // f16 (u16)
  float* a1   = p; p += 64*1024;
  float* a2   = p; p += 64*512;
  float* a3   = p; p += 64*256;
  float* a4   = p; p += 64*128;

  k_detect<<<1, 256, 0, stream>>>((const u32*)d_in[2], flagp);

  Jobs J;
  int nj = 0;
  auto add = [&](const void* s, float* d, int n, int f16 = 0) {
    J.j[nj].s = s; J.j[nj].d = d; J.j[nj].n = n; J.j[nj].f16 = f16; ++nj;
  };
  add(d_in[0],  x0,     64*64*64, 1);       // x0 straight to f16 for k_mf
  add(d_in[1],  cl1Wih, 512*64);
  add(d_in[2],  cl1Whh, 512*128);
  add(d_in[3],  cl1b,   512);
  add(d_in[4],  c2Wih,            512*128);
  add(d_in[7],  c2Wih + 512*128,  512*128);
  add(d_in[6],  c2bias,       512);
  add(d_in[9],  c2bias + 512, 512);
  add(d_in[5],  c2fWhh, 512*128);
  add(d_in[8],  c2bWhh, 512*128);
  add(d_in[10], c3Wih,            512*256);
  add(d_in[13], c3Wih + 512*256,  512*256);
  add(d_in[12], c3bias,       512);
  add(d_in[15], c3bias + 512, 512);
  add(d_in[11], c3fWhh, 512*128);
  add(d_in[14], c3bWhh, 512*128);
  add(d_in[16], ceWih,  512*256);
  add(d_in[17], ceWhh,  512*128);
  add(d_in[18], ceb,    512);
  add(d_in[19], cdWih,  512*128);
  add(d_in[20], cdWhh,  512*128);
  add(d_in[21], cdb,    512);
  add(d_in[22], cattW,  128*128);
  add(d_in[23], cattw,  128);
  add(d_in[25], cW1b,   1024);
  add(d_in[27], cW2b,   512);
  add(d_in[29], cW3b,   256);
  add(d_in[31], cW4b,   128);
  add(d_in[32], coW,    128);
  add(d_in[33], cob,    1);
  k_cvt_all<<<dim3(32, nj), 256, 0, stream>>>(J, flagp);

  PJobs P;
  for (int i = 0; i < 7; ++i) P.s2[i] = nullptr;
  P.s[0] = cl1Whh; P.d[0] = wpL1;
  P.s[1] = c2fWhh; P.d[1] = wp2f;
  P.s[2] = c2bWhh; P.d[2] = wp2b;
  P.s[3] = c3fWhh; P.d[3] = wp3f;
  P.s[4] = c3bWhh; P.d[4] = wp3b;
  P.s[5] = ceWhh;  P.d[5] = wpE;
  P.s[6] = cdWih;  P.s2[6] = cdWhh; P.d[6] = wpD;
  k_pack<<<dim3(128, 7), 256, 0, stream>>>(P);

  // lstm1 (MFMA: A = f16 x0)
  k_mf<<<dim3(64,8,1), 256, 0, stream>>>((const u16*)x0, 64, cl1Wih, 64, cl1b, Zf, 512, 64, 0, 0, flagp);
  k_rec<<<64, 512, 0, stream>>>(Zf, Zf, wpL1, wpL1, h1, 128, 0, 0, nullptr, nullptr, 0, 512, nullptr, 1);

  // biLSTM 2 (f+b input GEMM merged: N=1024, shared A = f16 h1)
  k_mf<<<dim3(64,16,1), 256, 0, stream>>>((const u16*)h1, 128, c2Wih, 128, c2bias, Z2, 1024, 128, 0, 0, flagp);
  k_rec<<<128, 512, 0, stream>>>(Z2, Z2 + 512, wp2f, wp2b, x2, 256, 0, 128, nullptr, nullptr, 0, 1024, nullptr, 1);

  // biLSTM 3 (merged, A = f16 x2)
  k_mf<<<dim3(64,16,1), 256, 0, stream>>>((const u16*)x2, 256, c3Wih, 256, c3bias, Z2, 1024, 256, 0, 0, flagp);
  k_rec<<<128, 512, 0, stream>>>(Z2, Z2 + 512, wp3f, wp3b, x3, 256, 0, 128, nullptr, nullptr, 0, 1024, nullptr, 1);

  // encoder (A = f16 x3); enco stays fp32 (att/proj/h0 consumers)
  k_mf<<<dim3(64,8,1), 256, 0, stream>>>((const u16*)x3, 256, ceWih, 256, ceb, Zf, 512, 256, 0, 0, flagp);
  k_rec<<<64, 512, 0, stream>>>(Zf, Zf, wpE, wpE, enco, 128, 0, 0, nullptr, nullptr, 0, 512, ec, 0);

  // decoder recurrence: h0 = enco[63], c0 = ec, Z = bias
  k_rec<<<64, 512, 0, stream>>>(cdb, cdb, wpD, wpD, Hdec, 128, 0, 0,
                                enco + (size_t)63*64*128, ec, 1, 512, nullptr, 0);

  // merged projection: [enco;Hdec] @ attW^T -> [encp;Hprj]  (M=8192, fp32)
  k_gemm<<<dim3(128,2,1), 256, 0, stream>>>(enco, 128, cattW, 128, nullptr, encp, 128, 128, 0, 0, 0, flagp);

  // attention -> flat [64, 16384] f16
  k_att<<<dim3(64,4), 256, 0, stream>>>(enco, encp, Hdec, Hprj, cattw, (u16*)flat);

  // MLP: bias-inits, then W1 on MFMA (split-K 64, atomic), tail on fp32 gemm
  IJobs I;
  I.b[0]=cW1b; I.d[0]=a1; I.n[0]=64*1024; I.mask[0]=1023;
  I.b[1]=cW2b; I.d[1]=a2; I.n[1]=64*512;  I.mask[1]=511;
  I.b[2]=cW3b; I.d[2]=a3; I.n[2]=64*256;  I.mask[2]=255;
  I.b[3]=cW4b; I.d[3]=a4; I.n[3]=64*128;  I.mask[3]=127;
  k_init4<<<dim3(64, 4), 256, 0, stream>>>(I);
  k_mf<<<dim3(1,16,64), 256, 0, stream>>>((const u16*)flat, 16384, d_in[24], 16384, nullptr, a1, 1024, 16384, 1, 1, flagp);
  k_gemm<<<dim3(1,8,16), 256, 0, stream>>>(a1, 1024, d_in[26], 1024, nullptr, a2, 512, 1024, 1, 1, 1, flagp);
  k_gemm<<<dim3(1,4,8), 256, 0, stream>>>(a2, 512, d_in[28], 512, nullptr, a3, 256, 512, 1, 1, 1, flagp);
  k_gemm<<<dim3(1,2,4), 256, 0, stream>>>(a3, 256, d_in[30], 256, nullptr, a4, 128, 256, 1, 1, 1, flagp);

  k_head<<<1, 64, 0, stream>>>(a4, coW, cob, d_out, flagp);
}

// Round 5
// 547.774 us; speedup vs baseline: 1.1847x; 1.1847x over previous
//
#include <hip/hip_runtime.h>
#include <hip/hip_bf16.h>

typedef unsigned int u32;
typedef unsigned short u16;

typedef _Float16 half2_t __attribute__((ext_vector_type(2)));
union H2U { u32 u; half2_t h; };

typedef _Float16 f16x8 __attribute__((ext_vector_type(8)));
typedef float f32x4 __attribute__((ext_vector_type(4)));
union F16V { uint4 u; f16x8 h; };

#if defined(__has_builtin)
#if __has_builtin(__builtin_amdgcn_fdot2)
#define HAS_FDOT2 1
#endif
#if __has_builtin(__builtin_amdgcn_update_dpp)
#define HAS_DPP 1
#endif
#endif

__device__ __forceinline__ float bf2f(u32 u) {
  union { u32 i; float f; } v; v.i = u << 16; return v.f;
}
__device__ __forceinline__ float sigf(float x) {
  return 1.0f / (1.0f + __expf(-x));
}
__device__ __forceinline__ float tanhfast(float x) {
  return 2.0f / (1.0f + __expf(-2.0f * x)) - 1.0f;
}
__device__ __forceinline__ u16 f2bf(float f) {
  u32 u = __float_as_uint(f);
  u += 0x7fffu + ((u >> 16) & 1u);
  return (u16)(u >> 16);
}
__device__ __forceinline__ u16 f2h(float f) {
  union { _Float16 h; u16 u; } v; v.h = (_Float16)f; return v.u;
}
__device__ __forceinline__ u32 fpair2h2(float a, float b) {
  H2U r; r.h.x = (_Float16)a; r.h.y = (_Float16)b; return r.u;
}
__device__ __forceinline__ u32 bfpair2h2(u32 two_bf) {
  H2U r;
  r.h.x = (_Float16)bf2f(two_bf & 0xffffu);
  r.h.y = (_Float16)bf2f(two_bf >> 16);
  return r.u;
}
__device__ __forceinline__ float dot2acc(u32 wu, u32 hu, float acc) {
  H2U w, h; w.u = wu; h.u = hu;
#ifdef HAS_FDOT2
  return __builtin_amdgcn_fdot2(w.h, h.h, acc, false);
#else
  acc = fmaf((float)w.h.x, (float)h.h.x, acc);
  return fmaf((float)w.h.y, (float)h.h.y, acc);
#endif
}
// DPP cross-lane move (VALU pipe, not DS). Controls used:
//   0xB1 quad_perm[1,0,3,2] (xor 1), 0x4E quad_perm[2,3,0,1] (xor 2),
//   0x00/0x55/0xAA/0xFF quad broadcast lane k, 0x104 row_shl:4 (shfl_down 4).
template <int CTRL>
__device__ __forceinline__ float dppf(float x) {
#ifdef HAS_DPP
  int y = __builtin_amdgcn_update_dpp(0, __float_as_int(x), CTRL, 0xF, 0xF, true);
  return __int_as_float(y);
#else
  const int lane = threadIdx.x & 63;
  if (CTRL == 0xB1)  return __shfl_xor(x, 1, 64);
  if (CTRL == 0x4E)  return __shfl_xor(x, 2, 64);
  if (CTRL == 0x104) return __shfl_down(x, 4, 64);
  return __shfl(x, (lane & ~3) | (CTRL & 3), 64);  // quad broadcast
#endif
}

// ---- runtime dtype detection (bf16 vs fp32 inputs) ----
__global__ void k_detect(const u32* __restrict__ w, int* __restrict__ flag) {
  __shared__ int cnt;
  if (threadIdx.x == 0) cnt = 0;
  __syncthreads();
  int c = 0;
  for (int i = threadIdx.x; i < 8192; i += 256) {
    const u32 lo = w[i] & 0xffffu;
    const u32 e = (lo >> 7) & 0xffu;
    c += (e >= 100u && e <= 140u) ? 1 : 0;
  }
  atomicAdd(&cnt, c);
  __syncthreads();
  if (threadIdx.x == 0) *flag = (cnt > 4915) ? 1 : 0;
}

struct Job { const void* s; float* d; int n; int f16; };
struct Jobs { Job j[30]; };

__global__ void k_cvt_all(Jobs J, const int* __restrict__ flag) {
  const Job jb = J.j[blockIdx.y];
  const int isbf = *flag;
  for (int i = blockIdx.x * 256 + threadIdx.x; i < jb.n; i += 32 * 256) {
    const float v = isbf ? bf2f(((const u16*)jb.s)[i]) : ((const float*)jb.s)[i];
    if (jb.f16) ((u16*)jb.d)[i] = f2h(v);
    else        jb.d[i] = v;
  }
}

// 4 bias-broadcast inits in one dispatch
struct IJobs { const float* b[4]; float* d[4]; int n[4]; int mask[4]; };
__global__ void k_init4(IJobs I) {
  const int j = blockIdx.y;
  const float* bb = I.b[j];
  float* dd = I.d[j];
  const int n = I.n[j], mask = I.mask[j];
  for (int i = blockIdx.x * 256 + threadIdx.x; i < n; i += gridDim.x * 256)
    dd[i] = bb[i & mask];
}

// Pack staged fp32 recurrent weights into the per-thread f16-pair layout
// consumed by k_rec (round-2 proven layout): thread (r=tid>>2, kq=tid&3)
// owns rows r+128j x k-chunk kq:
//   dst[tid*64 + j*16 + kk] = pack(W[r+128j][kq*32+2kk], ..+1).
// Optional second source s2 -> element-wise sum (decoder Wih+Whh).
struct PJobs { const float* s[7]; const float* s2[7]; u32* d[7]; };
__global__ void k_pack(PJobs P) {
  const float* src = P.s[blockIdx.y];
  const float* src2 = P.s2[blockIdx.y];
  u32* dst = P.d[blockIdx.y];
  const int i = blockIdx.x * 256 + threadIdx.x;   // 0..32767
  const int tid = i >> 6, rem = i & 63;
  const int j = rem >> 4, kk = rem & 15;
  const int r = tid >> 2, kq = tid & 3;
  const int row = r + 128 * j, col = kq * 32 + 2 * kk;
  float v0 = src[row * 128 + col];
  float v1 = src[row * 128 + col + 1];
  if (src2) { v0 += src2[row * 128 + col]; v1 += src2[row * 128 + col + 1]; }
  H2U v;
  v.h.x = (_Float16)v0;
  v.h.y = (_Float16)v1;
  dst[i] = v.u;
}

// MFMA f16 GEMM: C[M,N] (+)= A[M,K] @ W[N,K]^T (+bias).
// A: f16 (u16) row-major. W: bf16-u16 or fp32 (wfollow: runtime detect; else
// fp32 staged), converted to f16 in-flight (exact for bf16 at these ranges).
// 64x64 tile, 4 waves x (2x2) 16x16x32 frags, LDS rows padded to 40 u16
// (80 B = 20 banks -> worst 2-way = free). Verified C/D map: col=lane&15,
// row=(lane>>4)*4+reg.
__launch_bounds__(256)
__global__ void k_mf(const u16* __restrict__ A, int lda,
                     const void* __restrict__ Wv, int ldw,
                     const float* __restrict__ bias,
                     float* __restrict__ C, int ldc,
                     int K, int atom, int wfollow,
                     const int* __restrict__ dflag)
{
  __shared__ __align__(16) u16 As[64][40];
  __shared__ __align__(16) u16 Bs[64][40];
  const int isbf = wfollow ? *dflag : 0;
  const int tid = threadIdx.x;
  const int m0 = blockIdx.x * 64, n0 = blockIdx.y * 64;
  const int kc = K / gridDim.z;
  const int k0 = blockIdx.z * kc;
  const int row = tid >> 2, part = tid & 3;       // staging: 8 cols of one row
  const int l = tid & 63, w = tid >> 6;
  const int wr = w >> 1, wc = w & 1;              // wave tile origin /32
  const int fr = l & 15, fk = l >> 4;             // fragment row/col, k-group
  f32x4 acc[2][2] = {};
  const u16*   Ap   = A + (size_t)(m0 + row) * lda + k0 + part * 8;
  const u16*   Wp16 = (const u16*)Wv   + (size_t)(n0 + row) * ldw + k0 + part * 8;
  const float* Wp32 = (const float*)Wv + (size_t)(n0 + row) * ldw + k0 + part * 8;

  for (int kk = 0; kk < kc; kk += 32) {
    const uint4 av = *(const uint4*)(Ap + kk);
    uint4 wv;
    if (isbf) {
      const uint4 wu = *(const uint4*)(Wp16 + kk);
      wv.x = bfpair2h2(wu.x); wv.y = bfpair2h2(wu.y);
      wv.z = bfpair2h2(wu.z); wv.w = bfpair2h2(wu.w);
    } else {
      const float4 w0 = *(const float4*)(Wp32 + kk);
      const float4 w1 = *(const float4*)(Wp32 + kk + 4);
      wv.x = fpair2h2(w0.x, w0.y); wv.y = fpair2h2(w0.z, w0.w);
      wv.z = fpair2h2(w1.x, w1.y); wv.w = fpair2h2(w1.z, w1.w);
    }
    __syncthreads();
    *(uint4*)&As[row][part * 8] = av;
    *(uint4*)&Bs[row][part * 8] = wv;
    __syncthreads();
    F16V a0, a1, b0, b1;
    a0.u = *(const uint4*)&As[wr * 32 + fr][fk * 8];
    a1.u = *(const uint4*)&As[wr * 32 + 16 + fr][fk * 8];
    b0.u = *(const uint4*)&Bs[wc * 32 + fr][fk * 8];
    b1.u = *(const uint4*)&Bs[wc * 32 + 16 + fr][fk * 8];
    acc[0][0] = __builtin_amdgcn_mfma_f32_16x16x32_f16(a0.h, b0.h, acc[0][0], 0, 0, 0);
    acc[0][1] = __builtin_amdgcn_mfma_f32_16x16x32_f16(a0.h, b1.h, acc[0][1], 0, 0, 0);
    acc[1][0] = __builtin_amdgcn_mfma_f32_16x16x32_f16(a1.h, b0.h, acc[1][0], 0, 0, 0);
    acc[1][1] = __builtin_amdgcn_mfma_f32_16x16x32_f16(a1.h, b1.h, acc[1][1], 0, 0, 0);
  }

  #pragma unroll
  for (int i = 0; i < 2; ++i) {
    #pragma unroll
    for (int j = 0; j < 2; ++j) {
      const int n = n0 + wc * 32 + j * 16 + fr;
      const float bv = (bias && !atom) ? bias[n] : 0.0f;
      #pragma unroll
      for (int q = 0; q < 4; ++q) {
        const int m = m0 + wr * 32 + i * 16 + fk * 4 + q;
        if (atom) atomicAdd(&C[(size_t)m * ldc + n], acc[i][j][q]);
        else      C[(size_t)m * ldc + n] = acc[i][j][q] + bv;
      }
    }
  }
}

// C[M,N] (+)= A[M,K] @ W[N,K]^T (+bias). fp32 scalar path — retained for the
// small proj + MLP-tail layers (actA tanh on A, fp32 accumulate).
__launch_bounds__(256)
__global__ void k_gemm(const float* __restrict__ A, int lda,
                       const void* __restrict__ Wv, int ldw,
                       const float* __restrict__ bias,
                       float* __restrict__ C, int ldc,
                       int K, int actA, int atom, int wfollow,
                       const int* __restrict__ dflag)
{
  __shared__ float As[32][65];
  __shared__ float Ws[32][65];
  const int isbf = wfollow ? *dflag : 0;
  const int tid = threadIdx.x;
  const int tx = tid & 15, ty = tid >> 4;
  const int m0 = blockIdx.x * 64, n0 = blockIdx.y * 64;
  const int kc = K / gridDim.z;
  const int k0 = blockIdx.z * kc;
  const int lr = tid >> 2;
  const int lk = (tid & 3) << 3;
  float acc[4][4] = {{0.f}};
  const float* Ap   = A + (size_t)(m0 + lr) * lda + k0 + lk;
  const u16*   Wp16 = (const u16*)Wv   + (size_t)(n0 + lr) * ldw + k0 + lk;
  const float* Wp32 = (const float*)Wv + (size_t)(n0 + lr) * ldw + k0 + lk;
  for (int kk = 0; kk < kc; kk += 32) {
    float4 av0 = *(const float4*)(Ap + kk);
    float4 av1 = *(const float4*)(Ap + kk + 4);
    float wv[8];
    if (isbf) {
      const uint4 wu = *(const uint4*)(Wp16 + kk);
      wv[0]=bf2f(wu.x & 0xffffu); wv[1]=bf2f(wu.x >> 16);
      wv[2]=bf2f(wu.y & 0xffffu); wv[3]=bf2f(wu.y >> 16);
      wv[4]=bf2f(wu.z & 0xffffu); wv[5]=bf2f(wu.z >> 16);
      wv[6]=bf2f(wu.w & 0xffffu); wv[7]=bf2f(wu.w >> 16);
    } else {
      const float4 w0 = *(const float4*)(Wp32 + kk);
      const float4 w1 = *(const float4*)(Wp32 + kk + 4);
      wv[0]=w0.x; wv[1]=w0.y; wv[2]=w0.z; wv[3]=w0.w;
      wv[4]=w1.x; wv[5]=w1.y; wv[6]=w1.z; wv[7]=w1.w;
    }
    if (actA) {
      av0.x = tanhfast(av0.x); av0.y = tanhfast(av0.y);
      av0.z = tanhfast(av0.z); av0.w = tanhfast(av0.w);
      av1.x = tanhfast(av1.x); av1.y = tanhfast(av1.y);
      av1.z = tanhfast(av1.z); av1.w = tanhfast(av1.w);
    }
    __syncthreads();
    As[lk+0][lr] = av0.x; As[lk+1][lr] = av0.y;
    As[lk+2][lr] = av0.z; As[lk+3][lr] = av0.w;
    As[lk+4][lr] = av1.x; As[lk+5][lr] = av1.y;
    As[lk+6][lr] = av1.z; As[lk+7][lr] = av1.w;
    #pragma unroll
    for (int q = 0; q < 8; ++q) Ws[lk+q][lr] = wv[q];
    __syncthreads();
    #pragma unroll
    for (int k = 0; k < 32; ++k) {
      float a[4], w[4];
      #pragma unroll
      for (int i = 0; i < 4; ++i) a[i] = As[k][ty + 16*i];
      #pragma unroll
      for (int j = 0; j < 4; ++j) w[j] = Ws[k][tx + 16*j];
      #pragma unroll
      for (int i = 0; i < 4; ++i)
        #pragma unroll
        for (int j = 0; j < 4; ++j)
          acc[i][j] = fmaf(a[i], w[j], acc[i][j]);
    }
  }
  #pragma unroll
  for (int i = 0; i < 4; ++i) {
    const int m = m0 + ty + 16*i;
    #pragma unroll
    for (int j = 0; j < 4; ++j) {
      const int n = n0 + tx + 16*j;
      if (atom) atomicAdd(&C[(size_t)m*ldc + n], acc[i][j]);
      else {
        const float bv = bias ? bias[n] : 0.0f;
        C[(size_t)m*ldc + n] = acc[i][j] + bv;
      }
    }
  }
}

// Recurrence — EXACT round-2 proven structure (51.2us/dispatch): gate-spread
// DPP, hbuf[2][64], per-step global h store, __syncthreads barrier.
// ONE change vs round-2: single-transcendental gate activation. Lane kq needs
// only sig(g) (kq!=2) or tanh(g) (kq==2); tanh(g) = 2*sig(2g)-1, so compute
// one exp+rcp instead of two (exp/rcp are quarter-rate: saves ~64 issue-cy
// per step per SIMD). R3 lgkm-barrier and R4 8-chunk remap both REGRESSED —
// do not reintroduce.
__launch_bounds__(512)
__attribute__((amdgpu_waves_per_eu(2, 2)))
__global__ void k_rec(const float* __restrict__ Zf, const float* __restrict__ Zb,
                      const u32* __restrict__ Wf, const u32* __restrict__ Wb,
                      float* __restrict__ HS, int hstride, int offF, int offB,
                      const float* __restrict__ h0, const float* __restrict__ c0,
                      int zmode, int zld, float* __restrict__ Cout, int hf16)
{
  const int b = blockIdx.x & 63;
  const int dir = blockIdx.x >> 6;
  const float* Z = dir ? Zb : Zf;
  const u32* Wg = dir ? Wb : Wf;
  const int off = dir ? offB : offF;
  const int tid = threadIdx.x;
  const int r = tid >> 2, kq = tid & 3;

  __shared__ __align__(16) float zall[64*512];   // 128 KB staged Z (read-only in loop)
  __shared__ __align__(16) u32 hbuf[2][64];      // packed f16 h, double-buffered

  // --- bulk stage Z into LDS (coalesced float4), ^16 column swizzle on odd gates ---
  if (!zmode) {
    #pragma unroll
    for (int q = 0; q < 16; ++q) {
      const int fid = tid + 512*q;
      const int s = fid >> 7, c4 = (fid & 127) << 2;
      const int cs = c4 ^ (((c4 >> 7) & 1) << 4);
      *(float4*)&zall[s*512 + cs] = *(const float4*)&Z[((size_t)s*64 + b)*zld + c4];
    }
  }

  u32 wp[64];
  {
    const uint4* wr = (const uint4*)(Wg + (size_t)tid * 64);
    #pragma unroll
    for (int q = 0; q < 16; ++q) {
      const uint4 u = wr[q];
      wp[q*4+0]=u.x; wp[q*4+1]=u.y; wp[q*4+2]=u.z; wp[q*4+3]=u.w;
    }
  }
  #pragma unroll
  for (int q = 0; q < 64; ++q)
    asm volatile("" : "+v"(wp[q]));

  float creg = c0 ? c0[b*128 + r] : 0.0f;
  if (tid < 64) {
    H2U v;
    if (h0) {
      v.h.x = (_Float16)h0[b*128 + 2*tid];
      v.h.y = (_Float16)h0[b*128 + 2*tid + 1];
    } else {
      v.h.x = (_Float16)0.f; v.h.y = (_Float16)0.f;
    }
    hbuf[0][tid] = v.u;
  }

  // per-thread zc slot: gate kq, row r (matches the staging swizzle)
  const int colz = (r + 128*kq) ^ ((kq & 1) << 4);
  float zdec = 0.f;
  if (zmode) zdec = Z[r + 128*kq];
  const float* zp = zall + (dir ? 63*512 : 0) + colz;
  const int zstep = dir ? -512 : 512;
  size_t hidx = ((size_t)(dir ? 63 : 0)*64 + b)*hstride + off + r;
  const ptrdiff_t hstep = (ptrdiff_t)(dir ? -64 : 64) * hstride;
  const bool beta = (kq & 1) != 0;
  const bool gmm  = (kq & 2) != 0;
  const bool isg  = (kq == 2);
  __syncthreads();

  for (int t = 0; t < 64; ++t) {
    float zcv;
    if (zmode) zcv = zdec;
    else       zcv = *zp;
    u32 hh16[16];
    {
      const u32* hp = hbuf[t & 1];
      *(uint4*)&hh16[0]  = *(const uint4*)&hp[kq*16];
      *(uint4*)&hh16[4]  = *(const uint4*)&hp[kq*16 + 4];
      *(uint4*)&hh16[8]  = *(const uint4*)&hp[kq*16 + 8];
      *(uint4*)&hh16[12] = *(const uint4*)&hp[kq*16 + 12];
    }
    float a[4] = {0.f,0.f,0.f,0.f};
    #pragma unroll
    for (int j = 0; j < 4; ++j)
      #pragma unroll
      for (int i = 0; i < 16; ++i)
        a[j] = dot2acc(wp[j*16 + i], hh16[i], a[j]);
    // 4x4 quad transpose-reduce: lane kq ends with the full dot of gate kq.
    const float u0 = beta ? a[1] : a[0];
    const float v0 = beta ? a[0] : a[1];
    const float u1 = beta ? a[3] : a[2];
    const float v1 = beta ? a[2] : a[3];
    const float x01 = u0 + dppf<0xB1>(v0);
    const float x23 = u1 + dppf<0xB1>(v1);
    const float keep = gmm ? x23 : x01;
    const float send = gmm ? x01 : x23;
    const float g = keep + dppf<0x4E>(send) + zcv;
    // single transcendental: lane kq==2 gets tanh(g)=2*sig(2g)-1, others sig(g)
    const float s = sigf(isg ? g + g : g);
    const float val = isg ? s + s - 1.0f : s;
    const float si  = dppf<0x00>(val);
    const float sf  = dppf<0x55>(val);
    const float tgg = dppf<0xAA>(val);
    const float so  = dppf<0xFF>(val);
    const float cc = sf * creg + si * tgg;
    const float hh = so * tanhfast(cc);
    creg = cc;
    const float hn = dppf<0x104>(hh);
    if (kq == 0) {
      if (hf16) ((u16*)HS)[hidx] = f2h(hh);
      else      HS[hidx] = hh;
      if (!(r & 1)) {
        H2U v; v.h.x = (_Float16)hh; v.h.y = (_Float16)hn;
        hbuf[(t+1) & 1][r >> 1] = v.u;
      }
    }
    zp += zstep;
    hidx += hstep;
    __syncthreads();
  }

  if (Cout != nullptr && kq == 0) Cout[b*128 + r] = creg;
}

// Attention, fully parallel over (b, t-slice). flat is written as f16 (u16)
// — it feeds the MFMA W1 GEMM directly.
#define TS 132
__launch_bounds__(256, 1)
__global__ void k_att(const float* __restrict__ enco, const float* __restrict__ encp,
                      const float* __restrict__ Hdec, const float* __restrict__ Hproj,
                      const float* __restrict__ attw, u16* __restrict__ flat)
{
  const int b = blockIdx.x;
  const int t0 = blockIdx.y * 16;
  const int tid = threadIdx.x;
  __shared__ __align__(16) float ep[64*TS];
  __shared__ __align__(16) float en[64*TS];
  __shared__ __align__(16) float hp[16*TS];
  __shared__ float S[64*17];
  __shared__ float aw[64*17];
  __shared__ __align__(16) float awt[128];

  for (int i = tid; i < 8192; i += 256) {
    const int s = i >> 7, k = i & 127;
    const size_t g = ((size_t)s*64 + b)*128 + k;
    ep[s*TS + k] = encp[g];
    en[s*TS + k] = enco[g];
  }
  for (int i = tid; i < 2048; i += 256) {
    const int t = i >> 7, k = i & 127;
    const size_t g = ((size_t)(t0 + t)*64 + b)*128 + k;
    hp[t*TS + k] = Hproj[g];
    flat[(size_t)b*16384 + (t0 + t)*256 + k] = f2h(Hdec[g]);
  }
  if (tid < 128) awt[tid] = attw[tid];
  __syncthreads();

  {
    const int t = tid & 15, sg = tid >> 4;
    #pragma unroll
    for (int i = 0; i < 4; ++i) {
      const int s = sg*4 + i;
      float acc = 0.f;
      #pragma unroll 8
      for (int k = 0; k < 128; k += 4) {
        const float4 h4 = *(const float4*)&hp[t*TS + k];
        const float4 e4 = *(const float4*)&ep[s*TS + k];
        const float4 w4 = *(const float4*)&awt[k];
        acc = fmaf(w4.x, tanhfast(h4.x + e4.x), acc);
        acc = fmaf(w4.y, tanhfast(h4.y + e4.y), acc);
        acc = fmaf(w4.z, tanhfast(h4.z + e4.z), acc);
        acc = fmaf(w4.w, tanhfast(h4.w + e4.w), acc);
      }
      S[s*17 + t] = acc;
    }
  }
  __syncthreads();
  if (tid < 16) {
    const int t = tid;
    float m = -1e30f;
    for (int s = 0; s < 64; ++s) m = fmaxf(m, S[s*17 + t]);
    float sum = 0.f;
    for (int s = 0; s < 64; ++s) {
      const float e = __expf(S[s*17 + t] - m);
      aw[s*17 + t] = e;
      sum += e;
    }
    const float inv = 1.0f / sum;
    for (int s = 0; s < 64; ++s) aw[s*17 + t] *= inv;
  }
  __syncthreads();
  {
    const int t = tid >> 4, kg = tid & 15;
    float c0a[8] = {0,0,0,0,0,0,0,0};
    for (int s = 0; s < 64; ++s) {
      const float a = aw[s*17 + t];
      const float4 e0 = *(const float4*)&en[s*TS + kg*8];
      const float4 e1 = *(const float4*)&en[s*TS + kg*8 + 4];
      c0a[0] = fmaf(a, e0.x, c0a[0]);
      c0a[1] = fmaf(a, e0.y, c0a[1]);
      c0a[2] = fmaf(a, e0.z, c0a[2]);
      c0a[3] = fmaf(a, e0.w, c0a[3]);
      c0a[4] = fmaf(a, e1.x, c0a[4]);
      c0a[5] = fmaf(a, e1.y, c0a[5]);
      c0a[6] = fmaf(a, e1.z, c0a[6]);
      c0a[7] = fmaf(a, e1.w, c0a[7]);
    }
    union { u16 s[8]; uint4 u; } o;
    #pragma unroll
    for (int q = 0; q < 8; ++q) o.s[q] = f2h(c0a[q]);
    u16* dst = &flat[(size_t)b*16384 + (t0 + t)*256 + 128 + kg*8];
    *(uint4*)dst = o.u;
  }
}

__global__ void k_head(const float* __restrict__ a4, const float* __restrict__ outW,
                       const float* __restrict__ outb, void* __restrict__ out,
                       const int* __restrict__ dflag)
{
  const int b = threadIdx.x;
  float acc = outb[0];
  #pragma unroll 8
  for (int k = 0; k < 128; ++k)
    acc = fmaf(outW[k], tanhfast(a4[b*128 + k]), acc);
  if (*dflag) ((u16*)out)[b] = f2bf(acc);
  else        ((float*)out)[b] = acc;
}

extern "C" void kernel_launch(void* const* d_in, const int* in_sizes, int n_in,
                              void* d_out, int out_size, void* d_ws, size_t ws_size,
                              hipStream_t stream)
{
  (void)in_sizes; (void)n_in; (void)out_size; (void)ws_size;

  float* p = (float*)d_ws;
  int*   flagp = (int*)p;    p += 64;
  float* x0    = p; p += 64*64*64;          // f16 (u16)
  float* cl1Wih = p; p += 512*64;
  float* cl1Whh = p; p += 512*128;
  float* cl1b   = p; p += 512;
  float* c2Wih  = p; p += 1024*128;
  float* c2bias = p; p += 1024;
  float* c2fWhh = p; p += 512*128;
  float* c2bWhh = p; p += 512*128;
  float* c3Wih  = p; p += 1024*256;
  float* c3bias = p; p += 1024;
  float* c3fWhh = p; p += 512*128;
  float* c3bWhh = p; p += 512*128;
  float* ceWih  = p; p += 512*256;
  float* ceWhh  = p; p += 512*128;
  float* ceb    = p; p += 512;
  float* cdWih  = p; p += 512*128;
  float* cdWhh  = p; p += 512*128;
  float* cdb    = p; p += 512;
  float* cattW  = p; p += 128*128;
  float* cattw  = p; p += 128;
  float* cW1b   = p; p += 1024;
  float* cW2b   = p; p += 512;
  float* cW3b   = p; p += 256;
  float* cW4b   = p; p += 128;
  float* coW    = p; p += 128;
  float* cob    = p; p += 16;
  u32* wpL1 = (u32*)p; p += 32768;
  u32* wp2f = (u32*)p; p += 32768;
  u32* wp2b = (u32*)p; p += 32768;
  u32* wp3f = (u32*)p; p += 32768;
  u32* wp3b = (u32*)p; p += 32768;
  u32* wpE  = (u32*)p; p += 32768;
  u32* wpD  = (u32*)p; p += 32768;
  float* Zf   = p; p += 4096*512;
  float* Z2   = p; p += 4096*1024;
  float* h1   = p; p += 4096*128;           // f16 (u16)
  float* x2   = p; p += 4096*256;           // f16 (u16)
  float* x3   = p; p += 4096*256;           // f16 (u16)
  float* enco = p; p += 4096*128;   // enco and Hdec contiguous (merged proj A)
  float* Hdec = p; p += 4096*128;
  float* encp = p; p += 4096*128;   // encp and Hprj contiguous (merged proj C)
  float* Hprj = p; p += 4096*128;
  float* ec   = p; p += 64*128;
  float* flat = p; p += 64*16384;           // f16 (u16)
  float* a1   = p; p += 64*1024;
  float* a2   = p; p += 64*512;
  float* a3   = p; p += 64*256;
  float* a4   = p; p += 64*128;

  k_detect<<<1, 256, 0, stream>>>((const u32*)d_in[2], flagp);

  Jobs J;
  int nj = 0;
  auto add = [&](const void* s, float* d, int n, int f16 = 0) {
    J.j[nj].s = s; J.j[nj].d = d; J.j[nj].n = n; J.j[nj].f16 = f16; ++nj;
  };
  add(d_in[0],  x0,     64*64*64, 1);       // x0 straight to f16 for k_mf
  add(d_in[1],  cl1Wih, 512*64);
  add(d_in[2],  cl1Whh, 512*128);
  add(d_in[3],  cl1b,   512);
  add(d_in[4],  c2Wih,            512*128);
  add(d_in[7],  c2Wih + 512*128,  512*128);
  add(d_in[6],  c2bias,       512);
  add(d_in[9],  c2bias + 512, 512);
  add(d_in[5],  c2fWhh, 512*128);
  add(d_in[8],  c2bWhh, 512*128);
  add(d_in[10], c3Wih,            512*256);
  add(d_in[13], c3Wih + 512*256,  512*256);
  add(d_in[12], c3bias,       512);
  add(d_in[15], c3bias + 512, 512);
  add(d_in[11], c3fWhh, 512*128);
  add(d_in[14], c3bWhh, 512*128);
  add(d_in[16], ceWih,  512*256);
  add(d_in[17], ceWhh,  512*128);
  add(d_in[18], ceb,    512);
  add(d_in[19], cdWih,  512*128);
  add(d_in[20], cdWhh,  512*128);
  add(d_in[21], cdb,    512);
  add(d_in[22], cattW,  128*128);
  add(d_in[23], cattw,  128);
  add(d_in[25], cW1b,   1024);
  add(d_in[27], cW2b,   512);
  add(d_in[29], cW3b,   256);
  add(d_in[31], cW4b,   128);
  add(d_in[32], coW,    128);
  add(d_in[33], cob,    1);
  k_cvt_all<<<dim3(32, nj), 256, 0, stream>>>(J, flagp);

  PJobs P;
  for (int i = 0; i < 7; ++i) P.s2[i] = nullptr;
  P.s[0] = cl1Whh; P.d[0] = wpL1;
  P.s[1] = c2fWhh; P.d[1] = wp2f;
  P.s[2] = c2bWhh; P.d[2] = wp2b;
  P.s[3] = c3fWhh; P.d[3] = wp3f;
  P.s[4] = c3bWhh; P.d[4] = wp3b;
  P.s[5] = ceWhh;  P.d[5] = wpE;
  P.s[6] = cdWih;  P.s2[6] = cdWhh; P.d[6] = wpD;
  k_pack<<<dim3(128, 7), 256, 0, stream>>>(P);

  // lstm1 (MFMA: A = f16 x0)
  k_mf<<<dim3(64,8,1), 256, 0, stream>>>((const u16*)x0, 64, cl1Wih, 64, cl1b, Zf, 512, 64, 0, 0, flagp);
  k_rec<<<64, 512, 0, stream>>>(Zf, Zf, wpL1, wpL1, h1, 128, 0, 0, nullptr, nullptr, 0, 512, nullptr, 1);

  // biLSTM 2 (f+b input GEMM merged: N=1024, shared A = f16 h1)
  k_mf<<<dim3(64,16,1), 256, 0, stream>>>((const u16*)h1, 128, c2Wih, 128, c2bias, Z2, 1024, 128, 0, 0, flagp);
  k_rec<<<128, 512, 0, stream>>>(Z2, Z2 + 512, wp2f, wp2b, x2, 256, 0, 128, nullptr, nullptr, 0, 1024, nullptr, 1);

  // biLSTM 3 (merged, A = f16 x2)
  k_mf<<<dim3(64,16,1), 256, 0, stream>>>((const u16*)x2, 256, c3Wih, 256, c3bias, Z2, 1024, 256, 0, 0, flagp);
  k_rec<<<128, 512, 0, stream>>>(Z2, Z2 + 512, wp3f, wp3b, x3, 256, 0, 128, nullptr, nullptr, 0, 1024, nullptr, 1);

  // encoder (A = f16 x3); enco stays fp32 (att/proj/h0 consumers)
  k_mf<<<dim3(64,8,1), 256, 0, stream>>>((const u16*)x3, 256, ceWih, 256, ceb, Zf, 512, 256, 0, 0, flagp);
  k_rec<<<64, 512, 0, stream>>>(Zf, Zf, wpE, wpE, enco, 128, 0, 0, nullptr, nullptr, 0, 512, ec, 0);

  // decoder recurrence: h0 = enco[63], c0 = ec, Z = bias
  k_rec<<<64, 512, 0, stream>>>(cdb, cdb, wpD, wpD, Hdec, 128, 0, 0,
                                enco + (size_t)63*64*128, ec, 1, 512, nullptr, 0);

  // merged projection: [enco;Hdec] @ attW^T -> [encp;Hprj]  (M=8192, fp32)
  k_gemm<<<dim3(128,2,1), 256, 0, stream>>>(enco, 128, cattW, 128, nullptr, encp, 128, 128, 0, 0, 0, flagp);

  // attention -> flat [64, 16384] f16
  k_att<<<dim3(64,4), 256, 0, stream>>>(enco, encp, Hdec, Hprj, cattw, (u16*)flat);

  // MLP: bias-inits, then W1 on MFMA (split-K 64, atomic), tail on fp32 gemm
  IJobs I;
  I.b[0]=cW1b; I.d[0]=a1; I.n[0]=64*1024; I.mask[0]=1023;
  I.b[1]=cW2b; I.d[1]=a2; I.n[1]=64*512;  I.mask[1]=511;
  I.b[2]=cW3b; I.d[2]=a3; I.n[2]=64*256;  I.mask[2]=255;
  I.b[3]=cW4b; I.d[3]=a4; I.n[3]=64*128;  I.mask[3]=127;
  k_init4<<<dim3(64, 4), 256, 0, stream>>>(I);
  k_mf<<<dim3(1,16,64), 256, 0, stream>>>((const u16*)flat, 16384, d_in[24], 16384, nullptr, a1, 1024, 16384, 1, 1, flagp);
  k_gemm<<<dim3(1,8,16), 256, 0, stream>>>(a1, 1024, d_in[26], 1024, nullptr, a2, 512, 1024, 1, 1, 1, flagp);
  k_gemm<<<dim3(1,4,8), 256, 0, stream>>>(a2, 512, d_in[28], 512, nullptr, a3, 256, 512, 1, 1, 1, flagp);
  k_gemm<<<dim3(1,2,4), 256, 0, stream>>>(a3, 256, d_in[30], 256, nullptr, a4, 128, 256, 1, 1, 1, flagp);

  k_head<<<1, 64, 0, stream>>>(a4, coW, cob, d_out, flagp);
}